// Round 16
// baseline (239.878 us; speedup 1.0000x reference)
//
#include <hip/hip_runtime.h>

// Problem constants (from reference)
constexpr int B   = 4;
constexpr int CF  = 3;    // feat channels
constexpr int CM  = 21;   // mask channels
constexpr int H   = 128;
constexpr int W   = 128;
constexpr int KS  = 7;
constexpr int PAD = 3;
constexpr int CENTER = (KS * KS) / 2;  // 24
constexpr int NNB = KS * KS - 1;       // 48 neighbors
constexpr int NUM_ITER = 10;

constexpr int TILE  = 16;
constexpr int TH    = TILE + 2 * PAD;  // 22
constexpr int TS    = 24;              // LDS row stride: 2-way aliasing only (free)
constexpr int PLANE = TH * TS;         // 528
constexpr int HW    = H * W;
constexpr int NBLK  = (W / TILE) * (H / TILE) * B;  // 256 blocks == 256 CUs -> co-resident

// Cross-XCD-coherent access path for the mask ping-pong (L2-bypassing flagged
// ops, NO cache invalidation anywhere). RELAXED = no fence instructions.
__device__ __forceinline__ float ldm(const float* p) {
    return __hip_atomic_load(p, __ATOMIC_RELAXED, __HIP_MEMORY_SCOPE_AGENT);
}
__device__ __forceinline__ void stm(float* p, float v) {
    __hip_atomic_store(p, v, __ATOMIC_RELAXED, __HIP_MEMORY_SCOPE_AGENT);
}

// ---------------------------------------------------------------------------
// Persistent fused kernel (R6 structure, fence-free barrier).
// 256 blocks (1/CU, co-resident by construction), 768 thr = 12 waves/CU.
// aff lives in 48 registers; mask traffic via agent-scope relaxed atomics;
// barrier = syncthreads (vmcnt drain) + release-add + RELAXED spin.
// ---------------------------------------------------------------------------
__global__ __launch_bounds__(768) void fused_kernel(const float* __restrict__ feats,
                                                    const float* __restrict__ mask,
                                                    float* __restrict__ out,
                                                    float* __restrict__ buf0,
                                                    float* __restrict__ buf1,
                                                    unsigned int* __restrict__ ctr) {
    __shared__ float tile[CM][TH][TS];   // 44.4 KB
    float* tf = &tile[0][0][0];

    const int tx = threadIdx.x, ty = threadIdx.y, tz = threadIdx.z;
    const int bx = blockIdx.x * TILE, by = blockIdx.y * TILE;
    const int b  = blockIdx.z;
    const int tid = (tz * TILE + ty) * TILE + tx;
    const int h = by + ty, w = bx + tx;

    // One staging slot per thread (484 halo words per plane, 768 threads)
    const bool sv = tid < TH * TH;
    int gof = 0, lof = 0;
    if (sv) {
        const int r = tid / TH, q = tid - r * TH;
        const int gh = min(max(by + r - PAD, 0), H - 1);
        const int gw = min(max(bx + q - PAD, 0), W - 1);
        gof = gh * W + gw;
        lof = r * TS + q;
    }

    // ---- Phase 1: feats -> LDS, affinity weights into 48 registers ----
    if (sv) {
        const float* fb = feats + (size_t)b * CF * HW;
        #pragma unroll
        for (int c = 0; c < CF; ++c) tf[c * PLANE + lof] = fb[c * HW + gof];
    }
    __syncthreads();

    float qv[CF], inv[CF];
    #pragma unroll
    for (int c = 0; c < CF; ++c) {
        const float* tp = tf + c * PLANE + ty * TS + tx;
        qv[c] = tp[PAD * TS + PAD];
        float s = 0.f, s2 = 0.f;
        #pragma unroll
        for (int i = 0; i < KS; ++i)
            #pragma unroll
            for (int j = 0; j < KS; ++j) {
                if (i == PAD && j == PAD) continue;
                const float v = tp[i * TS + j];
                s += v; s2 += v * v;
            }
        const float mean = s * (1.0f / NNB);
        const float var  = fmaxf(s2 - (float)NNB * mean * mean, 0.f) * (1.0f / (NNB - 1));
        inv[c] = 1.0f / (1e-8f + 0.1f * sqrtf(var));
    }

    float a[NNB];
    {
        float mx = -1e30f;
        #pragma unroll
        for (int i = 0; i < KS; ++i)
            #pragma unroll
            for (int j = 0; j < KS; ++j) {
                const int nn = i * KS + j;
                if (nn == CENTER) continue;
                const int n = (nn < CENTER) ? nn : nn - 1;
                float t = 0.f;
                #pragma unroll
                for (int c = 0; c < CF; ++c)
                    t += fabsf(tf[c * PLANE + (ty + i) * TS + (tx + j)] - qv[c]) * inv[c];
                a[n] = -t * (1.0f / CF);
                mx = fmaxf(mx, a[n]);
            }
        float ssum = 0.f;
        #pragma unroll
        for (int n = 0; n < NNB; ++n) { a[n] = __expf(a[n] - mx); ssum += a[n]; }
        const float rs = 1.0f / ssum;
        #pragma unroll
        for (int n = 0; n < NNB; ++n) a[n] *= rs;
    }
    __syncthreads();   // feats tile no longer needed

    // ---- Phase 2: 10 iterations, fence-free software grid barrier ----
    const int c0 = tz * (CM / 3);                 // 7 channels per z-slice
    const float* cur = mask + (size_t)b * CM * HW;

    for (int t = 0; t < NUM_ITER; ++t) {
        float* dstb = ((t == NUM_ITER - 1) ? out : ((t & 1) ? buf1 : buf0))
                      + (size_t)b * CM * HW;

        // stage all 21 channel halo tiles via the coherent path
        if (sv) {
            for (int c = 0; c < CM; ++c)
                tf[c * PLANE + lof] = ldm(cur + c * HW + gof);
        }
        __syncthreads();

        float* dp = dstb + h * W + w;
        for (int k = 0; k < CM / 3; ++k) {
            const int c = c0 + k;
            const float* tp = tf + c * PLANE + ty * TS + tx;
            float s = 0.f;
            #pragma unroll
            for (int i = 0; i < KS; ++i)
                #pragma unroll
                for (int j = 0; j < KS; ++j) {
                    const int nn = i * KS + j;
                    if (nn == CENTER) continue;
                    const int n = (nn < CENTER) ? nn : nn - 1;
                    s += a[n] * tp[i * TS + j];
                }
            stm(dp + c * HW, s);
        }
        cur = dstb;

        if (t < NUM_ITER - 1) {
            // All stores drained (syncthreads -> per-wave vmcnt(0)), at the
            // coherent point (L2-bypassed). Publish with ONE release-add;
            // readers spin RELAXED (no acquire, no invalidate) then reload
            // through the flagged path, which cannot hit stale L2.
            __syncthreads();
            if (tid == 0) {
                __hip_atomic_fetch_add(&ctr[t], 1u, __ATOMIC_RELEASE,
                                       __HIP_MEMORY_SCOPE_AGENT);
                while (__hip_atomic_load(&ctr[t], __ATOMIC_RELAXED,
                                         __HIP_MEMORY_SCOPE_AGENT) < (unsigned)NBLK)
                    __builtin_amdgcn_s_sleep(2);
            }
            __syncthreads();
        }
    }
}

// ---------------------------------------------------------------------------
extern "C" void kernel_launch(void* const* d_in, const int* in_sizes, int n_in,
                              void* d_out, int out_size, void* d_ws, size_t ws_size,
                              hipStream_t stream) {
    const float* feats = (const float*)d_in[0];
    const float* mask  = (const float*)d_in[1];
    float* out  = (float*)d_out;

    float* buf0 = (float*)d_ws;                          // 5.5 MB
    float* buf1 = buf0 + (size_t)B * CM * HW;            // 5.5 MB
    unsigned int* ctr = (unsigned int*)(buf1 + (size_t)B * CM * HW);  // 16 words

    // Zero the barrier counters every call (captured into the graph -> every replay)
    hipMemsetAsync(ctr, 0, 16 * sizeof(unsigned int), stream);

    dim3 blk(TILE, TILE, 3);
    dim3 grid(W / TILE, H / TILE, B);
    fused_kernel<<<grid, blk, 0, stream>>>(feats, mask, out, buf0, buf1, ctr);
}

// Round 17
// 143.978 us; speedup vs baseline: 1.6661x; 1.6661x over previous
//
#include <hip/hip_runtime.h>

// Problem constants (from reference)
constexpr int B   = 4;
constexpr int CF  = 3;    // feat channels
constexpr int CM  = 21;   // mask channels
constexpr int H   = 128;
constexpr int W   = 128;
constexpr int KS  = 7;
constexpr int PAD = 3;
constexpr int CENTER = (KS * KS) / 2;  // 24
constexpr int NNB = KS * KS - 1;       // 48 neighbors
constexpr int NUM_ITER = 10;

constexpr int TILE = 16;
constexpr int TH   = TILE + 2 * PAD;   // 22 (aff-kernel halo tile)
constexpr int TS   = 24;
constexpr int HW   = H * W;

// fuse-2 geometry
constexpr int IN   = TILE + 4 * PAD;   // 28 input halo tile
constexpr int IND  = 15;               // input LDS row stride in DWORDS (30 bf16; odd -> bank spread)
constexpr int MD   = 22;               // intermediate (iter t) region
constexpr int MDD  = 13;               // mid LDS row stride in DWORDS (26 bf16)
constexpr int CPB  = 7;                // channels per block (3 groups)
constexpr int NMID = MD * MD;          // 484 mid pixels

// bf16 helpers (round-to-nearest-even; no NaN in this data)
__device__ __forceinline__ unsigned short f2b(float v) {
    unsigned int x = __float_as_uint(v);
    x += 0x7fffu + ((x >> 16) & 1u);
    return (unsigned short)(x >> 16);
}
__device__ __forceinline__ float blo(unsigned int d) { return __uint_as_float(d << 16); }
__device__ __forceinline__ float bhi(unsigned int d) { return __uint_as_float(d & 0xffff0000u); }

// ---------------------------------------------------------------------------
// Kernel 1: per-pixel 48-way softmax affinity (validated R4-R15, unchanged).
// PLANE-major layout (coalesced): aff[((b*48 + n)*H + h)*W + w]
// ---------------------------------------------------------------------------
__global__ __launch_bounds__(256) void aff_kernel(const float* __restrict__ feats,
                                                  float* __restrict__ aff) {
    __shared__ float tile[CF][TH][TS];
    const int tx = threadIdx.x, ty = threadIdx.y;
    const int bx = blockIdx.x * TILE, by = blockIdx.y * TILE;
    const int b  = blockIdx.z;
    const int tid = ty * TILE + tx;

    for (int c = 0; c < CF; ++c) {
        const float* src = feats + (size_t)(b * CF + c) * HW;
        for (int idx = tid; idx < TH * TH; idx += 256) {
            const int r  = idx / TH, cc = idx - r * TH;
            const int gh = min(max(by + r  - PAD, 0), H - 1);
            const int gw = min(max(bx + cc - PAD, 0), W - 1);
            tile[c][r][cc] = src[gh * W + gw];
        }
    }
    __syncthreads();

    float q[CF], inv[CF];
    #pragma unroll
    for (int c = 0; c < CF; ++c) {
        const float* tp = &tile[c][ty][tx];
        q[c] = tp[PAD * TS + PAD];
        float s = 0.f, s2 = 0.f;
        #pragma unroll
        for (int i = 0; i < KS; ++i)
            #pragma unroll
            for (int j = 0; j < KS; ++j) {
                if (i == PAD && j == PAD) continue;
                const float v = tp[i * TS + j];
                s += v; s2 += v * v;
            }
        const float mean = s * (1.0f / NNB);
        const float var  = fmaxf(s2 - (float)NNB * mean * mean, 0.f) * (1.0f / (NNB - 1));
        inv[c] = 1.0f / (1e-8f + 0.1f * sqrtf(var));
    }

    float a[NNB];
    float mx = -1e30f;
    #pragma unroll
    for (int i = 0; i < KS; ++i)
        #pragma unroll
        for (int j = 0; j < KS; ++j) {
            const int nn = i * KS + j;
            if (nn == CENTER) continue;
            const int n = (nn < CENTER) ? nn : nn - 1;
            float t = 0.f;
            #pragma unroll
            for (int c = 0; c < CF; ++c)
                t += fabsf(tile[c][ty + i][tx + j] - q[c]) * inv[c];
            a[n] = -t * (1.0f / CF);
            mx = fmaxf(mx, a[n]);
        }
    float ssum = 0.f;
    #pragma unroll
    for (int n = 0; n < NNB; ++n) { a[n] = __expf(a[n] - mx); ssum += a[n]; }
    const float rs = 1.0f / ssum;

    const int h = by + ty, w = bx + tx;
    #pragma unroll
    for (int n = 0; n < NNB; ++n)
        aff[(((size_t)b * NNB + n) * H + h) * W + w] = a[n] * rs;
}

// ---------------------------------------------------------------------------
// Kernel 2: TWO fused iterations, bf16 LDS taps (2x LDS bandwidth).
// R15's validated geometry/sweep structure; window rows read as 4 dwords
// (8 bf16), per-lane parity handled by 7 cndmask selects. Accum f32;
// global ping-pong f32. One a[48] per thread, always unconditionally init'd.
// ---------------------------------------------------------------------------
__global__ __launch_bounds__(256, 3) void fuse2_kernel(const float* __restrict__ mi,
                                                       const float* __restrict__ aff,
                                                       float* __restrict__ mo) {
    __shared__ unsigned int in_u[CPB][IN][IND];   // bf16 pairs: 11.5 KB
    __shared__ unsigned int mid_u[CPB][MD][MDD];  // bf16 pairs:  7.4 KB

    const int tx = threadIdx.x, ty = threadIdx.y;
    const int tid = ty * TILE + tx;
    const int bx = blockIdx.x * TILE, by = blockIdx.y * TILE;
    const int zz = blockIdx.z;
    const int b  = zz / 3, g = zz % 3;
    const int c0 = g * CPB;

    const float* ab = aff + (size_t)b * NNB * HW;

    // ---- sweep-1 geometry (mid pixel m = tid < 484 always) + aff preload
    const int r1 = tid / MD, q1 = tid - r1 * MD;
    const int gh1 = min(max(by - PAD + r1, 0), H - 1);
    const int gw1 = min(max(bx - PAD + q1, 0), W - 1);

    float a[NNB];
    {
        const float* ap = ab + (size_t)gh1 * W + gw1;
        #pragma unroll
        for (int n = 0; n < NNB; ++n) a[n] = ap[(size_t)n * HW];
    }

    // ---- stage 28x28 x 7ch input halo as bf16 (edge-clamped)
    {
        const float* src = mi + (size_t)(b * CM + c0) * HW;
        for (int s = tid; s < IN * IN; s += 256) {
            const int rr = s / IN, qq = s - rr * IN;
            const int ih = min(max(by - 2 * PAD + rr, 0), H - 1);
            const int iw = min(max(bx - 2 * PAD + qq, 0), W - 1);
            const int go = ih * W + iw;
            #pragma unroll
            for (int c = 0; c < CPB; ++c)
                ((unsigned short*)&in_u[c][rr][0])[qq] = f2b(src[c * HW + go]);
        }
    }
    __syncthreads();

    // ==== pass 1, sweep 1: iteration t at mid pixel tid ====
    {
        const int ar = gh1 - by + PAD;        // window top row in in_t
        const int ac = gw1 - bx + PAD;        // window left col in in_t [0..21]
        const int k0 = (ac & ~1) >> 1;        // first dword of the 8-col span
        const bool par = (ac & 1);
        #pragma unroll
        for (int c = 0; c < CPB; ++c) {
            float s = 0.f;
            #pragma unroll
            for (int i = 0; i < KS; ++i) {
                const unsigned int* rp = &in_u[c][ar + i][0];
                const unsigned int d0 = rp[k0], d1 = rp[k0+1], d2 = rp[k0+2], d3 = rp[k0+3];
                const float e0=blo(d0), e1=bhi(d0), e2=blo(d1), e3=bhi(d1),
                            e4=blo(d2), e5=bhi(d2), e6=blo(d3), e7=bhi(d3);
                const float w0 = par?e1:e0, w1 = par?e2:e1, w2 = par?e3:e2,
                            w3 = par?e4:e3, w4 = par?e5:e4, w5 = par?e6:e5, w6 = par?e7:e6;
                const float wv[7] = { w0, w1, w2, w3, w4, w5, w6 };
                #pragma unroll
                for (int j = 0; j < KS; ++j) {
                    const int nn = i * KS + j;
                    if (nn == CENTER) continue;
                    const int n = (nn < CENTER) ? nn : nn - 1;
                    s += a[n] * wv[j];
                }
            }
            ((unsigned short*)&mid_u[c][r1][0])[q1] = f2b(s);
        }
    }

    // ==== pass 1, sweep 2: mid pixel tid+256 (clamped; store predicated) ====
    {
        const int m2 = (tid + 256 < NMID) ? tid + 256 : NMID - 1;
        const int r2 = m2 / MD, q2 = m2 - r2 * MD;
        const int gh2 = min(max(by - PAD + r2, 0), H - 1);
        const int gw2 = min(max(bx - PAD + q2, 0), W - 1);
        {
            const float* ap = ab + (size_t)gh2 * W + gw2;
            #pragma unroll
            for (int n = 0; n < NNB; ++n) a[n] = ap[(size_t)n * HW];
        }
        const int ar = gh2 - by + PAD;
        const int ac = gw2 - bx + PAD;
        const int k0 = (ac & ~1) >> 1;
        const bool par = (ac & 1);
        const bool wr = (tid + 256 < NMID);
        #pragma unroll
        for (int c = 0; c < CPB; ++c) {
            float s = 0.f;
            #pragma unroll
            for (int i = 0; i < KS; ++i) {
                const unsigned int* rp = &in_u[c][ar + i][0];
                const unsigned int d0 = rp[k0], d1 = rp[k0+1], d2 = rp[k0+2], d3 = rp[k0+3];
                const float e0=blo(d0), e1=bhi(d0), e2=blo(d1), e3=bhi(d1),
                            e4=blo(d2), e5=bhi(d2), e6=blo(d3), e7=bhi(d3);
                const float w0 = par?e1:e0, w1 = par?e2:e1, w2 = par?e3:e2,
                            w3 = par?e4:e3, w4 = par?e5:e4, w5 = par?e6:e5, w6 = par?e7:e6;
                const float wv[7] = { w0, w1, w2, w3, w4, w5, w6 };
                #pragma unroll
                for (int j = 0; j < KS; ++j) {
                    const int nn = i * KS + j;
                    if (nn == CENTER) continue;
                    const int n = (nn < CENTER) ? nn : nn - 1;
                    s += a[n] * wv[j];
                }
            }
            if (wr) ((unsigned short*)&mid_u[c][r2][0])[q2] = f2b(s);
        }
    }
    __syncthreads();

    // ==== pass 2: iteration t+1 at own output pixel (reload a[48]) ====
    {
        const int oh = by + ty, ow = bx + tx;
        {
            const float* ap = ab + (size_t)oh * W + ow;
            #pragma unroll
            for (int n = 0; n < NNB; ++n) a[n] = ap[(size_t)n * HW];
        }
        const int k0 = (tx & ~1) >> 1;        // window cols tx..tx+6 in mid coords
        const bool par = (tx & 1);
        float* dp = mo + (size_t)(b * CM + c0) * HW + (size_t)oh * W + ow;
        #pragma unroll
        for (int c = 0; c < CPB; ++c) {
            float s = 0.f;
            #pragma unroll
            for (int i = 0; i < KS; ++i) {
                const unsigned int* rp = &mid_u[c][ty + i][0];
                const unsigned int d0 = rp[k0], d1 = rp[k0+1], d2 = rp[k0+2], d3 = rp[k0+3];
                const float e0=blo(d0), e1=bhi(d0), e2=blo(d1), e3=bhi(d1),
                            e4=blo(d2), e5=bhi(d2), e6=blo(d3), e7=bhi(d3);
                const float w0 = par?e1:e0, w1 = par?e2:e1, w2 = par?e3:e2,
                            w3 = par?e4:e3, w4 = par?e5:e4, w5 = par?e6:e5, w6 = par?e7:e6;
                const float wv[7] = { w0, w1, w2, w3, w4, w5, w6 };
                #pragma unroll
                for (int j = 0; j < KS; ++j) {
                    const int nn = i * KS + j;
                    if (nn == CENTER) continue;
                    const int n = (nn < CENTER) ? nn : nn - 1;
                    s += a[n] * wv[j];
                }
            }
            dp[(size_t)c * HW] = s;
        }
    }
}

// ---------------------------------------------------------------------------
extern "C" void kernel_launch(void* const* d_in, const int* in_sizes, int n_in,
                              void* d_out, int out_size, void* d_ws, size_t ws_size,
                              hipStream_t stream) {
    const float* feats = (const float*)d_in[0];
    const float* mask  = (const float*)d_in[1];
    float* out = (float*)d_out;

    float* aff  = (float*)d_ws;                               // 12.58 MB (plane-major)
    float* buf0 = aff  + (size_t)B * NNB * HW;                // 5.5 MB
    float* buf1 = buf0 + (size_t)B * CM  * HW;                // 5.5 MB

    aff_kernel<<<dim3(W / TILE, H / TILE, B), dim3(TILE, TILE), 0, stream>>>(feats, aff);

    // 5 fused kernels = 10 iterations; last lands in d_out
    dim3 grid(W / TILE, H / TILE, B * 3);
    dim3 blk(TILE, TILE);
    fuse2_kernel<<<grid, blk, 0, stream>>>(mask, aff, buf0);
    fuse2_kernel<<<grid, blk, 0, stream>>>(buf0, aff, buf1);
    fuse2_kernel<<<grid, blk, 0, stream>>>(buf1, aff, buf0);
    fuse2_kernel<<<grid, blk, 0, stream>>>(buf0, aff, buf1);
    fuse2_kernel<<<grid, blk, 0, stream>>>(buf1, aff, out);
}